// Round 13
// baseline (270.895 us; speedup 1.0000x reference)
//
#include <hip/hip_runtime.h>
#include <hip/hip_bf16.h>
#include <cstdint>
#include <cstddef>

// B=4, S=2048, D=1024, H=16, DH=64.  BS = 8192 rows.
// VERBATIM revert to the Round-9 kernel (session best: 268.78 us, passed).
// R11/R12's fused V-transpose epilogue failed twice at ~2.2e-3 (unlocated
// schedule-sensitive race); per pre-commitment the fusion is retired.
// pack_all: W transposes via LDS (coalesced), x->bf16, bias pack
// gemm_qkv: QKV[8192][3072] bf16 (Q cols pre-scaled by 0.125*log2(e), bias
//           folded) — R7 128² counted-vmcnt dbuf.
// vt: V part of QKV -> Vtg[bh=64][e=64][s=2048] bf16 (global transpose)
// attn: 8 waves/block (256 q rows, 512 thr), grid 64x8 = 2 blocks/CU ->
//       16 waves/CU; 64-key double-buffered tiles, counted vmcnt(2).
// gemm_out: R7 128² counted-vmcnt dbuf.
// R5: T1 XCD-chunk swizzle on GEMM grids (confirmed -8.7 us).
// R7: counted-vmcnt dbuf K-loop on GEMMs (confirmed ~-12 us).
// R9: 8-wave attn blocks (confirmed -21 us).

typedef unsigned short u16;
typedef unsigned int u32;
typedef __attribute__((ext_vector_type(8))) __bf16 bf16x8;
typedef __attribute__((ext_vector_type(8))) unsigned short u16x8;
typedef __attribute__((ext_vector_type(4))) float f32x4;
typedef __attribute__((ext_vector_type(4))) unsigned int u32x4;

__device__ __forceinline__ u16 f2bf(float f) {
  union { __hip_bfloat16 h; u16 u; } c;
  c.h = __float2bfloat16(f);
  return c.u;
}
// Pack two f32 -> bf16x2 (RNE). Prefer the gfx950 HW instruction
// v_cvt_pk_bf16_f32 (1 VALU op); fallback: manual RNE (~6 VALU ops).
#if defined(__has_builtin)
#if __has_builtin(__builtin_amdgcn_cvt_pk_bf16_f32)
#define HAS_PK_BF16 1
#endif
#endif
__device__ __forceinline__ u32 pk2c(float a, float b) {
#ifdef HAS_PK_BF16
  return __builtin_bit_cast(u32, __builtin_amdgcn_cvt_pk_bf16_f32(a, b));
#else
  const u32 ua = __float_as_uint(a);
  const u32 ub = __float_as_uint(b);
  const u32 ra = ua + 0x7FFFu + ((ua >> 16) & 1u);
  const u32 rb = ub + 0x7FFFu + ((ub >> 16) & 1u);
  return (ra >> 16) | (rb & 0xFFFF0000u);
#endif
}
// exp2 via the amdgcn builtin (v_exp_f32). NOTE: __exp2f collides with a
// glibc math.h macro in this env — do not use it.
__device__ __forceinline__ float ex2(float x) {
  return __builtin_amdgcn_exp2f(x);
}

// async 16B global->LDS; LDS dest is wave-uniform base + lane*16.
__device__ __forceinline__ void async16(const void* g, void* l) {
  __builtin_amdgcn_global_load_lds(
      (const __attribute__((address_space(1))) void*)g,
      (__attribute__((address_space(3))) void*)l, 16, 0, 0);
}

// --------------------------------------------------------- merged packs ----
// grid [0,1024): 64x64 f32->bf16 LDS transposes (768 Wqkv + 256 Wo) —
//   coalesced 256B row reads + coalesced 128B row writes.
// grid [1024,9216): x->bf16 elementwise | [9216,9228): bias pack.
__global__ void k_pack_all(const float* __restrict__ x,
                           const float* __restrict__ Wq, const float* __restrict__ Wk,
                           const float* __restrict__ Wv,
                           const float* __restrict__ bq, const float* __restrict__ bk,
                           const float* __restrict__ bv,
                           const float* __restrict__ Wo,
                           u16* __restrict__ xb, u16* __restrict__ Wt,
                           float* __restrict__ bqkv, u16* __restrict__ Wot) {
  __shared__ __align__(16) u16 tile[64][72];
  const int bid = blockIdx.x;
  const int t = threadIdx.x;
  if (bid < 1024) {
    const float* src;
    u16* dstp;
    int rstride, n_base, d0;
    if (bid < 768) {     // Wt[proj*1024+h*64+e][d] = Wp[h][d][e]
      const int proj = bid >> 8, h = (bid >> 4) & 15, dt = bid & 15;
      const float* Wp = (proj == 0) ? Wq : ((proj == 1) ? Wk : Wv);
      src = Wp + h * 65536 + (dt * 64) * 64;
      rstride = 64;
      n_base = proj * 1024 + h * 64;
      d0 = dt * 64;
      dstp = Wt;
    } else {             // Wot[n][d] = Wo[d][n]
      const int tb = bid - 768, nt = tb >> 4, dt = tb & 15;
      src = Wo + (size_t)(dt * 64) * 1024 + nt * 64;
      rstride = 1024;
      n_base = nt * 64;
      d0 = dt * 64;
      dstp = Wot;
    }
    {  // read 64 rows x 64 cols, coalesced; convert; stage in LDS
      const int row = t >> 2, c0 = (t & 3) * 16;
      const float* s = src + row * rstride + c0;
#pragma unroll
      for (int j = 0; j < 4; ++j) {
        const float4 v = *(const float4*)(s + j * 4);
        ushort4 o;
        o.x = f2bf(v.x); o.y = f2bf(v.y); o.z = f2bf(v.z); o.w = f2bf(v.w);
        *(ushort4*)&tile[row][c0 + j * 4] = o;
      }
    }
    __syncthreads();
    {  // write transposed, coalesced (4 threads x 32B per output row)
      const int e = t >> 2, c0 = (t & 3) * 16;
      u16 buf[16];
#pragma unroll
      for (int i = 0; i < 16; ++i) buf[i] = tile[c0 + i][e];
      u16* d = dstp + (size_t)(n_base + e) * 1024 + d0 + c0;
      *(u16x8*)d = *(const u16x8*)&buf[0];
      *(u16x8*)(d + 8) = *(const u16x8*)&buf[8];
    }
  } else if (bid < 9216) {
    const int i = ((bid - 1024) * 256 + t) * 4;
    const float4 v = *(const float4*)(x + i);
    ushort4 o;
    o.x = f2bf(v.x); o.y = f2bf(v.y); o.z = f2bf(v.z); o.w = f2bf(v.w);
    *(ushort4*)(xb + i) = o;
  } else {
    const int n = (bid - 9216) * 256 + t;
    const int proj = n >> 10, rem = n & 1023, h = rem >> 6, e = rem & 63;
    const float* bp = (proj == 0) ? bq : ((proj == 1) ? bk : bv);
    bqkv[n] = bp[h * 64 + e];
  }
}

// ----------------------------------------------------------------- GEMM ----
// R7 128² counted-vmcnt dbuf. MODE 0: bf16 out, Q cols scaled by
// 0.125*log2e (exp2 domain). T1 XCD swizzle on the grid.
template <int MODE>
__global__ __launch_bounds__(256)
void k_gemm(const u16* __restrict__ A, const u16* __restrict__ Bt,
            const float* __restrict__ bias, void* __restrict__ Cout, int ldc) {
  __shared__ __align__(16) u16 Alds[2][4096];   // 2 x 8 KB
  __shared__ __align__(16) u16 Blds[2][4096];
  const int t = threadIdx.x;
  const int lane = t & 63;
  const int w = t >> 6;
  const int l15 = lane & 15;
  const int quad = lane >> 4;
  const int wm = w >> 1, wn = w & 1;

  // T1 XCD-chunk swizzle (requires nwg % 8 == 0: 1536 and 512 both ok)
  const int nwg = gridDim.x * gridDim.y;
  const int wg  = blockIdx.y * gridDim.x + blockIdx.x;
  const int q8  = nwg >> 3;
  const int swz = (wg & 7) * q8 + (wg >> 3);
  const int bx  = swz % gridDim.x;
  const int by  = swz / gridDim.x;
  const int m0 = by << 7;
  const int n0 = bx << 7;

  const u16* ga0 = A + (size_t)(m0 + (t >> 2)) * 1024 + (t & 3) * 8;
  const u16* ga1 = ga0 + (size_t)64 * 1024;
  const u16* gb0 = Bt + (size_t)(n0 + (t >> 2)) * 1024 + (t & 3) * 8;
  const u16* gb1 = gb0 + (size_t)64 * 1024;
  const int lofs0 = w * 512;          // u16 offset of this wave's chunk
  const int lofs1 = w * 512 + 2048;

  f32x4 acc[4][4];
#pragma unroll
  for (int mi = 0; mi < 4; ++mi)
#pragma unroll
    for (int ni = 0; ni < 4; ++ni) acc[mi][ni] = (f32x4){0.f, 0.f, 0.f, 0.f};

  // prologue: stage tile 0 -> buf 0
  async16(ga0, &Alds[0][lofs0]); async16(ga1, &Alds[0][lofs1]);
  async16(gb0, &Blds[0][lofs0]); async16(gb1, &Blds[0][lofs1]);
  ga0 += 32; ga1 += 32; gb0 += 32; gb1 += 32;

#define GEMM_COMPUTE(BUF)                                                     \
  {                                                                           \
    const u16* const Ab = &Alds[BUF][0];                                      \
    const u16* const Bb = &Blds[BUF][0];                                      \
    bf16x8 af[4], bfr[4];                                                     \
    _Pragma("unroll")                                                         \
    for (int i = 0; i < 4; ++i) {                                             \
      af[i]  = *(const bf16x8*)(Ab + (wm * 64 + i * 16 + l15) * 32 + quad * 8); \
      bfr[i] = *(const bf16x8*)(Bb + (wn * 64 + i * 16 + l15) * 32 + quad * 8); \
    }                                                                         \
    _Pragma("unroll")                                                         \
    for (int mi = 0; mi < 4; ++mi)                                            \
      _Pragma("unroll")                                                       \
      for (int ni = 0; ni < 4; ++ni)                                          \
        acc[mi][ni] = __builtin_amdgcn_mfma_f32_16x16x32_bf16(                \
            af[mi], bfr[ni], acc[mi][ni], 0, 0, 0);                           \
  }

#pragma unroll 2
  for (int kt = 0; kt < 31; ++kt) {
    const int cur = kt & 1, nxt = cur ^ 1;
    __builtin_amdgcn_s_barrier();   // all waves done reading buf[nxt]
    async16(ga0, &Alds[nxt][lofs0]); async16(ga1, &Alds[nxt][lofs1]);
    async16(gb0, &Blds[nxt][lofs0]); async16(gb1, &Blds[nxt][lofs1]);
    ga0 += 32; ga1 += 32; gb0 += 32; gb1 += 32;
    asm volatile("s_waitcnt vmcnt(4)" ::: "memory");  // tile kt landed; 4 in flight
    __builtin_amdgcn_s_barrier();   // every wave's tile-kt loads landed
    __builtin_amdgcn_sched_barrier(0);
    GEMM_COMPUTE(cur);
  }
  // epilogue: tile 31 is in buf[1]
  asm volatile("s_waitcnt vmcnt(0)" ::: "memory");
  __builtin_amdgcn_s_barrier();
  __builtin_amdgcn_sched_barrier(0);
  GEMM_COMPUTE(1);
#undef GEMM_COMPUTE

  const int row0 = m0 + wm * 64;
  const int col0 = n0 + wn * 64;
  const float qscale = (MODE == 0 && col0 < 1024) ? 0.125f * 1.4426950408889634f : 1.0f;
#pragma unroll
  for (int mi = 0; mi < 4; ++mi) {
#pragma unroll
    for (int ni = 0; ni < 4; ++ni) {
      const int col = col0 + ni * 16 + l15;
      const float bb = bias[col];
#pragma unroll
      for (int r = 0; r < 4; ++r) {
        const int row = row0 + mi * 16 + quad * 4 + r;
        const float v = (acc[mi][ni][r] + bb) * qscale;
        if (MODE == 0) ((u16*)Cout)[(size_t)row * ldc + col] = f2bf(v);
        else           ((float*)Cout)[(size_t)row * ldc + col] = v;
      }
    }
  }
}

// ------------------------------------------------- V global transpose ----
// Vtg[bh][e][s] = QKV[b*2048+s][2048 + h*64 + e]
__global__ __launch_bounds__(256)
void k_vt(const u16* __restrict__ qkv, u16* __restrict__ vtg) {
  __shared__ u16 tile[64][72];
  const int t = threadIdx.x;
  const int bh = blockIdx.y, b = bh >> 4, h = bh & 15;
  const int s0 = blockIdx.x << 6;
  {
    const int row = t >> 2, col0 = (t & 3) * 16;
    const u16* src = qkv + (size_t)(b * 2048 + s0 + row) * 3072 + 2048 + h * 64 + col0;
    const u16x8 v0 = *(const u16x8*)src;
    const u16x8 v1 = *(const u16x8*)(src + 8);
    *(u16x8*)&tile[row][col0] = v0;
    *(u16x8*)&tile[row][col0 + 8] = v1;
  }
  __syncthreads();
  {
    const int e = t >> 2, sc = (t & 3) * 16;
    u16 buf[16];
#pragma unroll
    for (int i = 0; i < 16; ++i) buf[i] = tile[sc + i][e];
    u16* dst = vtg + ((size_t)bh * 64 + e) * 2048 + s0 + sc;
    *(u16x8*)dst = *(const u16x8*)&buf[0];
    *(u16x8*)(dst + 8) = *(const u16x8*)&buf[8];
  }
}

// ------------------------------------------------------------- attention ----
// Block = (bh, 256 q rows), 8 waves x 32 q each. Grid (64 bh, 8 qtile)
// = 512 blocks = exactly 2/CU -> 16 waves/CU. XCD = bh&7 (x fastest).
//
// Staging (512 thr) writes the same LDS image as the R1 256-thr loop:
// lam = t>>3 in [0,64) spans the old (lam0, r) product:
//   key = pi(lam&31) + 32*(lam>>5), chunk = (t&7)^(lam&7)   [K]
//   e   = t>>3,                       chunk = (t&7)^(e&7)   [V]
// One async16 each per thread -> counted s_waitcnt vmcnt(2).
// Per tile: s_barrier; stage tile kt+1 -> other buffer; vmcnt(2);
// s_barrier; compute. Last-iter prefetch over-reads past QKV into MH /
// past Vtg into Wt — reads only, in-allocation, never consumed.
//
// Per K-tile: S^T = K.Q^T (A = K-frags from LDS under permutation pi; B =
// Q-frags in regs). Scores log2-domain -> p = exp2(s). Packed exp2 register
// pairs ARE the PV A-fragment for key-chunk ks. l via MFMA (B = ones):
// lacc rows match o rows -> scalar epilogue. setprio wraps MFMA clusters.
__global__ __launch_bounds__(512)
void k_attn(const u16* __restrict__ qkv, const u16* __restrict__ vtg,
            u16* __restrict__ mh) {
  // buffer b (u16 offsets): K at b*8192 (64 keys x 64), V at b*8192+4096 (64 e x 64)
  __shared__ __align__(16) u16 smem[16384];

  const int t = threadIdx.x;
  const int lane = t & 63;
  const int w = t >> 6;             // 0..7
  const int l15 = lane & 15;
  const int quad = lane >> 4;
  const int bh = blockIdx.x, b = bh >> 4, h = bh & 15;
  const int s0 = blockIdx.y << 8;   // 256 q rows per block

  // K staging: lam = t>>3 in [0,64) -> key pi(lam&31) + 32*(lam>>5)
  const int lam = t >> 3;
  const int key0 = ((lam & 3) | (((lam >> 2) & 3) << 3) | (((lam >> 4) & 1) << 2))
                   + ((lam >> 5) << 5);
  const int ck = (t & 7) ^ (lam & 7);
  const u16* kbase = qkv + (size_t)(b * 2048 + key0) * 3072 + 1024 + h * 64 + ck * 8;
  // V staging: e = t>>3 in [0,64), chunk = (t&7)^(e&7)
  const int ev = t >> 3;
  const int cv = (t & 7) ^ (ev & 7);
  const u16* vbase = vtg + ((size_t)bh * 64 + ev) * 2048 + cv * 8;

  // per-wave LDS staging bases (u16 offsets); HW adds lane*16B
  const int kofs = w * 512;          // + buf*8192
  const int vofs = 4096 + w * 512;   // + buf*8192

  // Q frags (B-operand) direct from global: q = s0 + w*32 + g*16 + l15
  bf16x8 aq[2][2];
#pragma unroll
  for (int g = 0; g < 2; ++g)
#pragma unroll
    for (int ks2 = 0; ks2 < 2; ++ks2)
      aq[g][ks2] = *(const bf16x8*)(qkv +
          (size_t)(b * 2048 + s0 + w * 32 + g * 16 + l15) * 3072 +
          h * 64 + ks2 * 32 + quad * 8);

  // all-ones B-frag for the l-MFMA (bf16 1.0 = 0x3F80)
  const u32x4 onesu = (u32x4){0x3F803F80u, 0x3F803F80u, 0x3F803F80u, 0x3F803F80u};
  const bf16x8 ones = __builtin_bit_cast(bf16x8, onesu);

  f32x4 o[2][4];
  f32x4 lacc[2];
#pragma unroll
  for (int g = 0; g < 2; ++g) {
    lacc[g] = (f32x4){0.f, 0.f, 0.f, 0.f};
#pragma unroll
    for (int ne = 0; ne < 4; ++ne) o[g][ne] = (f32x4){0.f, 0.f, 0.f, 0.f};
  }

  // prologue: tile 0 -> buffer 0
  async16(kbase, smem + kofs);
  async16(vbase, smem + vofs);
  kbase += 64 * 3072;
  vbase += 64;

#pragma unroll 2
  for (int kt = 0; kt < 32; ++kt) {
    const int cur = kt & 1;
    const u16* const Kc = smem + cur * 8192;
    const u16* const Vc = Kc + 4096;
    u16* const nb = smem + (cur ^ 1) * 8192;

    __builtin_amdgcn_s_barrier();   // all waves done reading buf[cur^1]
    // prefetch tile kt+1 into buf[cur^1] (unconditional; see OOB note above)
    async16(kbase, nb + kofs);
    async16(vbase, nb + vofs);
    kbase += 64 * 3072;
    vbase += 64;
    asm volatile("s_waitcnt vmcnt(2)" ::: "memory");  // tile kt landed; 2 in flight
    __builtin_amdgcn_s_barrier();   // every wave's tile-kt loads landed
    __builtin_amdgcn_sched_barrier(0);

#pragma unroll
    for (int ks = 0; ks < 2; ++ks) {
      u32x4 pf[2];  // per-g PV A-frag for key-chunk ks
#pragma unroll
      for (int h2 = 0; h2 < 2; ++h2) {
        const int row = (ks * 2 + h2) * 16 + l15;
        const bf16x8 kf0 = *(const bf16x8*)(Kc + row * 64 + ((quad) ^ (l15 & 7)) * 8);
        const bf16x8 kf1 = *(const bf16x8*)(Kc + row * 64 + ((4 + quad) ^ (l15 & 7)) * 8);
        f32x4 st[2];
        __builtin_amdgcn_s_setprio(1);
#pragma unroll
        for (int g = 0; g < 2; ++g) {
          st[g] = __builtin_amdgcn_mfma_f32_16x16x32_bf16(kf0, aq[g][0], (f32x4){0.f,0.f,0.f,0.f}, 0, 0, 0);
          st[g] = __builtin_amdgcn_mfma_f32_16x16x32_bf16(kf1, aq[g][1], st[g], 0, 0, 0);
        }
        __builtin_amdgcn_s_setprio(0);
#pragma unroll
        for (int g = 0; g < 2; ++g) {
          const float p0 = ex2(st[g][0]), p1 = ex2(st[g][1]);
          const float p2 = ex2(st[g][2]), p3 = ex2(st[g][3]);
          pf[g][h2 * 2 + 0] = pk2c(p0, p1);
          pf[g][h2 * 2 + 1] = pk2c(p2, p3);
        }
      }
      __builtin_amdgcn_s_setprio(1);
#pragma unroll
      for (int ne = 0; ne < 4; ++ne) {
        const int e = ne * 16 + l15;
        const bf16x8 bv8 = *(const bf16x8*)(Vc + e * 64 + ((ks * 4 + quad) ^ (e & 7)) * 8);
#pragma unroll
        for (int g = 0; g < 2; ++g)
          o[g][ne] = __builtin_amdgcn_mfma_f32_16x16x32_bf16(
              __builtin_bit_cast(bf16x8, pf[g]), bv8, o[g][ne], 0, 0, 0);
      }
#pragma unroll
      for (int g = 0; g < 2; ++g)
        lacc[g] = __builtin_amdgcn_mfma_f32_16x16x32_bf16(
            __builtin_bit_cast(bf16x8, pf[g]), ones, lacc[g], 0, 0, 0);
      __builtin_amdgcn_s_setprio(0);
    }
  }

  // epilogue: O row = quad*4+r within group; lacc has the SAME row layout,
  // so inv is per-(g,r) with no cross-lane traffic.
#pragma unroll
  for (int g = 0; g < 2; ++g) {
#pragma unroll
    for (int r = 0; r < 4; ++r) {
      const float iv = 1.f / lacc[g][r];
      const int row = s0 + w * 32 + g * 16 + quad * 4 + r;
#pragma unroll
      for (int ne = 0; ne < 4; ++ne) {
        const int col = h * 64 + ne * 16 + l15;
        mh[(size_t)(b * 2048 + row) * 1024 + col] = f2bf(o[g][ne][r] * iv);
      }
    }
  }
}

// ---------------------------------------------------------------- launch ----
extern "C" void kernel_launch(void* const* d_in, const int* in_sizes, int n_in,
                              void* d_out, int out_size, void* d_ws, size_t ws_size,
                              hipStream_t stream) {
  (void)in_sizes; (void)n_in; (void)out_size; (void)ws_size;
  const float* x  = (const float*)d_in[0];
  const float* Wq = (const float*)d_in[1];
  const float* bq = (const float*)d_in[2];
  const float* Wk = (const float*)d_in[3];
  const float* bk = (const float*)d_in[4];
  const float* Wv = (const float*)d_in[5];
  const float* bv = (const float*)d_in[6];
  const float* Wo = (const float*)d_in[7];
  const float* bo = (const float*)d_in[8];

  char* ws = (char*)d_ws;
  u16*   Xb   = (u16*)  (ws + 0);          // 16777216 B (dead after gemm_qkv)
  u16*   Vtg  = (u16*)  (ws + 0);          // aliases Xb, written after
  u16*   Wt   = (u16*)  (ws + 16777216);   //  6291456
  float* bqkv = (float*)(ws + 23068672);   //    12288
  u16*   Wot  = (u16*)  (ws + 23080960);   //  2097152
  u16*   QKV  = (u16*)  (ws + 25178112);   // 50331648
  u16*   MH   = (u16*)  (ws + 75509760);   // 16777216  (total ~92.3 MB)
  float* out  = (float*)d_out;

  k_pack_all <<<9228, 256, 0, stream>>>(x, Wq, Wk, Wv, bq, bk, bv, Wo,
                                        Xb, Wt, bqkv, Wot);
  k_gemm<0>  <<<dim3(24, 64), 256, 0, stream>>>(Xb, Wt, bqkv, (void*)QKV, 3072);
  k_vt       <<<dim3(32, 64), 256, 0, stream>>>(QKV, Vtg);
  k_attn     <<<dim3(64, 8), 512, 0, stream>>>(QKV, Vtg, MH);
  k_gemm<1>  <<<dim3(8, 64), 256, 0, stream>>>(MH, Wot, bo, (void*)out, 1024);
}

// Round 14
// 268.393 us; speedup vs baseline: 1.0093x; 1.0093x over previous
//
#include <hip/hip_runtime.h>
#include <hip/hip_bf16.h>
#include <cstdint>
#include <cstddef>

// B=4, S=2048, D=1024, H=16, DH=64.  BS = 8192 rows.
// Baseline = Round-9/13 kernel (session best, 268.8-270.9 us, passed).
// pack_all: W transposes via LDS (coalesced), x->bf16, bias pack
// gemm_qkv: QKV[8192][3072] bf16 (Q cols pre-scaled by 0.125*log2(e), bias
//           folded) — 128² counted-vmcnt dbuf (NBUF=2; 3-deep would cut
//           resident blocks 4->3 via 48KB LDS, m132-negative).
// vt: V part of QKV -> Vtg[bh=64][e=64][s=2048] bf16 (global transpose)
// attn: 8 waves/block (256 q rows, 512 thr), grid 64x8 = 2 blocks/CU ->
//       16 waves/CU; 64-key double-buffered tiles, counted vmcnt(2).
//       ~940 TF effective — at the documented plain-HIP frontier.
// gemm_out (R14): NBUF=3 staging (48KB LDS; grid 512 = 2 blocks/CU so
//       occupancy is unchanged — the only zero-risk lever left). Counted
//       vmcnt(8) main loop, 4->0 drain tail.
// R5: T1 XCD-chunk swizzle on GEMM grids (confirmed -8.7 us).
// R7: counted-vmcnt dbuf K-loop on GEMMs (confirmed ~-12 us).
// R9: 8-wave attn blocks (confirmed -21 us).

typedef unsigned short u16;
typedef unsigned int u32;
typedef __attribute__((ext_vector_type(8))) __bf16 bf16x8;
typedef __attribute__((ext_vector_type(8))) unsigned short u16x8;
typedef __attribute__((ext_vector_type(4))) float f32x4;
typedef __attribute__((ext_vector_type(4))) unsigned int u32x4;

__device__ __forceinline__ u16 f2bf(float f) {
  union { __hip_bfloat16 h; u16 u; } c;
  c.h = __float2bfloat16(f);
  return c.u;
}
// Pack two f32 -> bf16x2 (RNE). Prefer the gfx950 HW instruction
// v_cvt_pk_bf16_f32 (1 VALU op); fallback: manual RNE (~6 VALU ops).
#if defined(__has_builtin)
#if __has_builtin(__builtin_amdgcn_cvt_pk_bf16_f32)
#define HAS_PK_BF16 1
#endif
#endif
__device__ __forceinline__ u32 pk2c(float a, float b) {
#ifdef HAS_PK_BF16
  return __builtin_bit_cast(u32, __builtin_amdgcn_cvt_pk_bf16_f32(a, b));
#else
  const u32 ua = __float_as_uint(a);
  const u32 ub = __float_as_uint(b);
  const u32 ra = ua + 0x7FFFu + ((ua >> 16) & 1u);
  const u32 rb = ub + 0x7FFFu + ((ub >> 16) & 1u);
  return (ra >> 16) | (rb & 0xFFFF0000u);
#endif
}
// exp2 via the amdgcn builtin (v_exp_f32). NOTE: __exp2f collides with a
// glibc math.h macro in this env — do not use it.
__device__ __forceinline__ float ex2(float x) {
  return __builtin_amdgcn_exp2f(x);
}

// async 16B global->LDS; LDS dest is wave-uniform base + lane*16.
__device__ __forceinline__ void async16(const void* g, void* l) {
  __builtin_amdgcn_global_load_lds(
      (const __attribute__((address_space(1))) void*)g,
      (__attribute__((address_space(3))) void*)l, 16, 0, 0);
}

// --------------------------------------------------------- merged packs ----
// grid [0,1024): 64x64 f32->bf16 LDS transposes (768 Wqkv + 256 Wo) —
//   coalesced 256B row reads + coalesced 128B row writes.
// grid [1024,9216): x->bf16 elementwise | [9216,9228): bias pack.
__global__ void k_pack_all(const float* __restrict__ x,
                           const float* __restrict__ Wq, const float* __restrict__ Wk,
                           const float* __restrict__ Wv,
                           const float* __restrict__ bq, const float* __restrict__ bk,
                           const float* __restrict__ bv,
                           const float* __restrict__ Wo,
                           u16* __restrict__ xb, u16* __restrict__ Wt,
                           float* __restrict__ bqkv, u16* __restrict__ Wot) {
  __shared__ __align__(16) u16 tile[64][72];
  const int bid = blockIdx.x;
  const int t = threadIdx.x;
  if (bid < 1024) {
    const float* src;
    u16* dstp;
    int rstride, n_base, d0;
    if (bid < 768) {     // Wt[proj*1024+h*64+e][d] = Wp[h][d][e]
      const int proj = bid >> 8, h = (bid >> 4) & 15, dt = bid & 15;
      const float* Wp = (proj == 0) ? Wq : ((proj == 1) ? Wk : Wv);
      src = Wp + h * 65536 + (dt * 64) * 64;
      rstride = 64;
      n_base = proj * 1024 + h * 64;
      d0 = dt * 64;
      dstp = Wt;
    } else {             // Wot[n][d] = Wo[d][n]
      const int tb = bid - 768, nt = tb >> 4, dt = tb & 15;
      src = Wo + (size_t)(dt * 64) * 1024 + nt * 64;
      rstride = 1024;
      n_base = nt * 64;
      d0 = dt * 64;
      dstp = Wot;
    }
    {  // read 64 rows x 64 cols, coalesced; convert; stage in LDS
      const int row = t >> 2, c0 = (t & 3) * 16;
      const float* s = src + row * rstride + c0;
#pragma unroll
      for (int j = 0; j < 4; ++j) {
        const float4 v = *(const float4*)(s + j * 4);
        ushort4 o;
        o.x = f2bf(v.x); o.y = f2bf(v.y); o.z = f2bf(v.z); o.w = f2bf(v.w);
        *(ushort4*)&tile[row][c0 + j * 4] = o;
      }
    }
    __syncthreads();
    {  // write transposed, coalesced (4 threads x 32B per output row)
      const int e = t >> 2, c0 = (t & 3) * 16;
      u16 buf[16];
#pragma unroll
      for (int i = 0; i < 16; ++i) buf[i] = tile[c0 + i][e];
      u16* d = dstp + (size_t)(n_base + e) * 1024 + d0 + c0;
      *(u16x8*)d = *(const u16x8*)&buf[0];
      *(u16x8*)(d + 8) = *(const u16x8*)&buf[8];
    }
  } else if (bid < 9216) {
    const int i = ((bid - 1024) * 256 + t) * 4;
    const float4 v = *(const float4*)(x + i);
    ushort4 o;
    o.x = f2bf(v.x); o.y = f2bf(v.y); o.z = f2bf(v.z); o.w = f2bf(v.w);
    *(ushort4*)(xb + i) = o;
  } else {
    const int n = (bid - 9216) * 256 + t;
    const int proj = n >> 10, rem = n & 1023, h = rem >> 6, e = rem & 63;
    const float* bp = (proj == 0) ? bq : ((proj == 1) ? bk : bv);
    bqkv[n] = bp[h * 64 + e];
  }
}

// ----------------------------------------------------------------- GEMM ----
// 128² counted-vmcnt multi-buffer. MODE 0: bf16 out, Q cols scaled by
// 0.125*log2e (exp2 domain). T1 XCD swizzle on the grid.
// NBUF buffers: prologue stages tiles 0..NBUF-2; main loop (kt<33-NBUF)
// stages tile kt+NBUF-1 and waits vmcnt(4*(NBUF-1)); tail drains 4->0.
template <int MODE, int NBUF>
__global__ __launch_bounds__(256)
void k_gemm(const u16* __restrict__ A, const u16* __restrict__ Bt,
            const float* __restrict__ bias, void* __restrict__ Cout, int ldc) {
  __shared__ __align__(16) u16 Alds[NBUF][4096];   // NBUF x 8 KB
  __shared__ __align__(16) u16 Blds[NBUF][4096];
  const int t = threadIdx.x;
  const int lane = t & 63;
  const int w = t >> 6;
  const int l15 = lane & 15;
  const int quad = lane >> 4;
  const int wm = w >> 1, wn = w & 1;

  // T1 XCD-chunk swizzle (requires nwg % 8 == 0: 1536 and 512 both ok)
  const int nwg = gridDim.x * gridDim.y;
  const int wg  = blockIdx.y * gridDim.x + blockIdx.x;
  const int q8  = nwg >> 3;
  const int swz = (wg & 7) * q8 + (wg >> 3);
  const int bx  = swz % gridDim.x;
  const int by  = swz / gridDim.x;
  const int m0 = by << 7;
  const int n0 = bx << 7;

  const u16* ga0 = A + (size_t)(m0 + (t >> 2)) * 1024 + (t & 3) * 8;
  const u16* ga1 = ga0 + (size_t)64 * 1024;
  const u16* gb0 = Bt + (size_t)(n0 + (t >> 2)) * 1024 + (t & 3) * 8;
  const u16* gb1 = gb0 + (size_t)64 * 1024;
  const int lofs0 = w * 512;          // u16 offset of this wave's chunk
  const int lofs1 = w * 512 + 2048;

  f32x4 acc[4][4];
#pragma unroll
  for (int mi = 0; mi < 4; ++mi)
#pragma unroll
    for (int ni = 0; ni < 4; ++ni) acc[mi][ni] = (f32x4){0.f, 0.f, 0.f, 0.f};

#define GEMM_STAGE(BUF)                                                       \
  async16(ga0, &Alds[BUF][lofs0]); async16(ga1, &Alds[BUF][lofs1]);           \
  async16(gb0, &Blds[BUF][lofs0]); async16(gb1, &Blds[BUF][lofs1]);           \
  ga0 += 32; ga1 += 32; gb0 += 32; gb1 += 32;

#define GEMM_COMPUTE(BUF)                                                     \
  {                                                                           \
    const u16* const Ab = &Alds[BUF][0];                                      \
    const u16* const Bb = &Blds[BUF][0];                                      \
    bf16x8 af[4], bfr[4];                                                     \
    _Pragma("unroll")                                                         \
    for (int i = 0; i < 4; ++i) {                                             \
      af[i]  = *(const bf16x8*)(Ab + (wm * 64 + i * 16 + l15) * 32 + quad * 8); \
      bfr[i] = *(const bf16x8*)(Bb + (wn * 64 + i * 16 + l15) * 32 + quad * 8); \
    }                                                                         \
    _Pragma("unroll")                                                         \
    for (int mi = 0; mi < 4; ++mi)                                            \
      _Pragma("unroll")                                                       \
      for (int ni = 0; ni < 4; ++ni)                                          \
        acc[mi][ni] = __builtin_amdgcn_mfma_f32_16x16x32_bf16(                \
            af[mi], bfr[ni], acc[mi][ni], 0, 0, 0);                           \
  }

  // prologue: stage tiles 0..NBUF-2
#pragma unroll
  for (int p = 0; p < NBUF - 1; ++p) { GEMM_STAGE(p) }

  int bc = 0;                 // buffer holding the tile being computed
  int bs = NBUF - 1;          // buffer receiving the staged tile
#pragma unroll 2
  for (int kt = 0; kt < 33 - NBUF; ++kt) {
    __builtin_amdgcn_s_barrier();   // all waves done reading buf[bs]
    GEMM_STAGE(bs)                  // stage tile kt+NBUF-1 (<= 31, no OOB)
    bs = (bs + 1 == NBUF) ? 0 : bs + 1;
    if constexpr (NBUF == 2) {
      asm volatile("s_waitcnt vmcnt(4)" ::: "memory");   // tile kt landed
    } else {
      asm volatile("s_waitcnt vmcnt(8)" ::: "memory");   // tile kt landed
    }
    __builtin_amdgcn_s_barrier();   // every wave's tile-kt loads landed
    __builtin_amdgcn_sched_barrier(0);
    GEMM_COMPUTE(bc);
    bc = (bc + 1 == NBUF) ? 0 : bc + 1;
  }
  // drain tail: tiles 33-NBUF .. 31
  if constexpr (NBUF == 3) {
    asm volatile("s_waitcnt vmcnt(4)" ::: "memory");
    __builtin_amdgcn_s_barrier();
    __builtin_amdgcn_sched_barrier(0);
    GEMM_COMPUTE(bc);
    bc = (bc + 1 == NBUF) ? 0 : bc + 1;
  }
  asm volatile("s_waitcnt vmcnt(0)" ::: "memory");
  __builtin_amdgcn_s_barrier();
  __builtin_amdgcn_sched_barrier(0);
  GEMM_COMPUTE(bc);
#undef GEMM_STAGE
#undef GEMM_COMPUTE

  const int row0 = m0 + wm * 64;
  const int col0 = n0 + wn * 64;
  const float qscale = (MODE == 0 && col0 < 1024) ? 0.125f * 1.4426950408889634f : 1.0f;
#pragma unroll
  for (int mi = 0; mi < 4; ++mi) {
#pragma unroll
    for (int ni = 0; ni < 4; ++ni) {
      const int col = col0 + ni * 16 + l15;
      const float bb = bias[col];
#pragma unroll
      for (int r = 0; r < 4; ++r) {
        const int row = row0 + mi * 16 + quad * 4 + r;
        const float v = (acc[mi][ni][r] + bb) * qscale;
        if (MODE == 0) ((u16*)Cout)[(size_t)row * ldc + col] = f2bf(v);
        else           ((float*)Cout)[(size_t)row * ldc + col] = v;
      }
    }
  }
}

// ------------------------------------------------- V global transpose ----
// Vtg[bh][e][s] = QKV[b*2048+s][2048 + h*64 + e]
__global__ __launch_bounds__(256)
void k_vt(const u16* __restrict__ qkv, u16* __restrict__ vtg) {
  __shared__ u16 tile[64][72];
  const int t = threadIdx.x;
  const int bh = blockIdx.y, b = bh >> 4, h = bh & 15;
  const int s0 = blockIdx.x << 6;
  {
    const int row = t >> 2, col0 = (t & 3) * 16;
    const u16* src = qkv + (size_t)(b * 2048 + s0 + row) * 3072 + 2048 + h * 64 + col0;
    const u16x8 v0 = *(const u16x8*)src;
    const u16x8 v1 = *(const u16x8*)(src + 8);
    *(u16x8*)&tile[row][col0] = v0;
    *(u16x8*)&tile[row][col0 + 8] = v1;
  }
  __syncthreads();
  {
    const int e = t >> 2, sc = (t & 3) * 16;
    u16 buf[16];
#pragma unroll
    for (int i = 0; i < 16; ++i) buf[i] = tile[sc + i][e];
    u16* dst = vtg + ((size_t)bh * 64 + e) * 2048 + s0 + sc;
    *(u16x8*)dst = *(const u16x8*)&buf[0];
    *(u16x8*)(dst + 8) = *(const u16x8*)&buf[8];
  }
}

// ------------------------------------------------------------- attention ----
// Block = (bh, 256 q rows), 8 waves x 32 q each. Grid (64 bh, 8 qtile)
// = 512 blocks = exactly 2/CU -> 16 waves/CU. XCD = bh&7 (x fastest).
//
// Staging (512 thr) writes the same LDS image as the R1 256-thr loop:
// lam = t>>3 in [0,64) spans the old (lam0, r) product:
//   key = pi(lam&31) + 32*(lam>>5), chunk = (t&7)^(lam&7)   [K]
//   e   = t>>3,                       chunk = (t&7)^(e&7)   [V]
// One async16 each per thread -> counted s_waitcnt vmcnt(2).
// Per tile: s_barrier; stage tile kt+1 -> other buffer; vmcnt(2);
// s_barrier; compute. Last-iter prefetch over-reads past QKV into MH /
// past Vtg into Wt — reads only, in-allocation, never consumed.
//
// Per K-tile: S^T = K.Q^T (A = K-frags from LDS under permutation pi; B =
// Q-frags in regs). Scores log2-domain -> p = exp2(s). Packed exp2 register
// pairs ARE the PV A-fragment for key-chunk ks. l via MFMA (B = ones):
// lacc rows match o rows -> scalar epilogue. setprio wraps MFMA clusters.
__global__ __launch_bounds__(512)
void k_attn(const u16* __restrict__ qkv, const u16* __restrict__ vtg,
            u16* __restrict__ mh) {
  // buffer b (u16 offsets): K at b*8192 (64 keys x 64), V at b*8192+4096 (64 e x 64)
  __shared__ __align__(16) u16 smem[16384];

  const int t = threadIdx.x;
  const int lane = t & 63;
  const int w = t >> 6;             // 0..7
  const int l15 = lane & 15;
  const int quad = lane >> 4;
  const int bh = blockIdx.x, b = bh >> 4, h = bh & 15;
  const int s0 = blockIdx.y << 8;   // 256 q rows per block

  // K staging: lam = t>>3 in [0,64) -> key pi(lam&31) + 32*(lam>>5)
  const int lam = t >> 3;
  const int key0 = ((lam & 3) | (((lam >> 2) & 3) << 3) | (((lam >> 4) & 1) << 2))
                   + ((lam >> 5) << 5);
  const int ck = (t & 7) ^ (lam & 7);
  const u16* kbase = qkv + (size_t)(b * 2048 + key0) * 3072 + 1024 + h * 64 + ck * 8;
  // V staging: e = t>>3 in [0,64), chunk = (t&7)^(e&7)
  const int ev = t >> 3;
  const int cv = (t & 7) ^ (ev & 7);
  const u16* vbase = vtg + ((size_t)bh * 64 + ev) * 2048 + cv * 8;

  // per-wave LDS staging bases (u16 offsets); HW adds lane*16B
  const int kofs = w * 512;          // + buf*8192
  const int vofs = 4096 + w * 512;   // + buf*8192

  // Q frags (B-operand) direct from global: q = s0 + w*32 + g*16 + l15
  bf16x8 aq[2][2];
#pragma unroll
  for (int g = 0; g < 2; ++g)
#pragma unroll
    for (int ks2 = 0; ks2 < 2; ++ks2)
      aq[g][ks2] = *(const bf16x8*)(qkv +
          (size_t)(b * 2048 + s0 + w * 32 + g * 16 + l15) * 3072 +
          h * 64 + ks2 * 32 + quad * 8);

  // all-ones B-frag for the l-MFMA (bf16 1.0 = 0x3F80)
  const u32x4 onesu = (u32x4){0x3F803F80u, 0x3F803F80u, 0x3F803F80u, 0x3F803F80u};
  const bf16x8 ones = __builtin_bit_cast(bf16x8, onesu);

  f32x4 o[2][4];
  f32x4 lacc[2];
#pragma unroll
  for (int g = 0; g < 2; ++g) {
    lacc[g] = (f32x4){0.f, 0.f, 0.f, 0.f};
#pragma unroll
    for (int ne = 0; ne < 4; ++ne) o[g][ne] = (f32x4){0.f, 0.f, 0.f, 0.f};
  }

  // prologue: tile 0 -> buffer 0
  async16(kbase, smem + kofs);
  async16(vbase, smem + vofs);
  kbase += 64 * 3072;
  vbase += 64;

#pragma unroll 2
  for (int kt = 0; kt < 32; ++kt) {
    const int cur = kt & 1;
    const u16* const Kc = smem + cur * 8192;
    const u16* const Vc = Kc + 4096;
    u16* const nb = smem + (cur ^ 1) * 8192;

    __builtin_amdgcn_s_barrier();   // all waves done reading buf[cur^1]
    // prefetch tile kt+1 into buf[cur^1] (unconditional; see OOB note above)
    async16(kbase, nb + kofs);
    async16(vbase, nb + vofs);
    kbase += 64 * 3072;
    vbase += 64;
    asm volatile("s_waitcnt vmcnt(2)" ::: "memory");  // tile kt landed; 2 in flight
    __builtin_amdgcn_s_barrier();   // every wave's tile-kt loads landed
    __builtin_amdgcn_sched_barrier(0);

#pragma unroll
    for (int ks = 0; ks < 2; ++ks) {
      u32x4 pf[2];  // per-g PV A-frag for key-chunk ks
#pragma unroll
      for (int h2 = 0; h2 < 2; ++h2) {
        const int row = (ks * 2 + h2) * 16 + l15;
        const bf16x8 kf0 = *(const bf16x8*)(Kc + row * 64 + ((quad) ^ (l15 & 7)) * 8);
        const bf16x8 kf1 = *(const bf16x8*)(Kc + row * 64 + ((4 + quad) ^ (l15 & 7)) * 8);
        f32x4 st[2];
        __builtin_amdgcn_s_setprio(1);
#pragma unroll
        for (int g = 0; g < 2; ++g) {
          st[g] = __builtin_amdgcn_mfma_f32_16x16x32_bf16(kf0, aq[g][0], (f32x4){0.f,0.f,0.f,0.f}, 0, 0, 0);
          st[g] = __builtin_amdgcn_mfma_f32_16x16x32_bf16(kf1, aq[g][1], st[g], 0, 0, 0);
        }
        __builtin_amdgcn_s_setprio(0);
#pragma unroll
        for (int g = 0; g < 2; ++g) {
          const float p0 = ex2(st[g][0]), p1 = ex2(st[g][1]);
          const float p2 = ex2(st[g][2]), p3 = ex2(st[g][3]);
          pf[g][h2 * 2 + 0] = pk2c(p0, p1);
          pf[g][h2 * 2 + 1] = pk2c(p2, p3);
        }
      }
      __builtin_amdgcn_s_setprio(1);
#pragma unroll
      for (int ne = 0; ne < 4; ++ne) {
        const int e = ne * 16 + l15;
        const bf16x8 bv8 = *(const bf16x8*)(Vc + e * 64 + ((ks * 4 + quad) ^ (e & 7)) * 8);
#pragma unroll
        for (int g = 0; g < 2; ++g)
          o[g][ne] = __builtin_amdgcn_mfma_f32_16x16x32_bf16(
              __builtin_bit_cast(bf16x8, pf[g]), bv8, o[g][ne], 0, 0, 0);
      }
#pragma unroll
      for (int g = 0; g < 2; ++g)
        lacc[g] = __builtin_amdgcn_mfma_f32_16x16x32_bf16(
            __builtin_bit_cast(bf16x8, pf[g]), ones, lacc[g], 0, 0, 0);
      __builtin_amdgcn_s_setprio(0);
    }
  }

  // epilogue: O row = quad*4+r within group; lacc has the SAME row layout,
  // so inv is per-(g,r) with no cross-lane traffic.
#pragma unroll
  for (int g = 0; g < 2; ++g) {
#pragma unroll
    for (int r = 0; r < 4; ++r) {
      const float iv = 1.f / lacc[g][r];
      const int row = s0 + w * 32 + g * 16 + quad * 4 + r;
#pragma unroll
      for (int ne = 0; ne < 4; ++ne) {
        const int col = h * 64 + ne * 16 + l15;
        mh[(size_t)(b * 2048 + row) * 1024 + col] = f2bf(o[g][ne][r] * iv);
      }
    }
  }
}

// ---------------------------------------------------------------- launch ----
extern "C" void kernel_launch(void* const* d_in, const int* in_sizes, int n_in,
                              void* d_out, int out_size, void* d_ws, size_t ws_size,
                              hipStream_t stream) {
  (void)in_sizes; (void)n_in; (void)out_size; (void)ws_size;
  const float* x  = (const float*)d_in[0];
  const float* Wq = (const float*)d_in[1];
  const float* bq = (const float*)d_in[2];
  const float* Wk = (const float*)d_in[3];
  const float* bk = (const float*)d_in[4];
  const float* Wv = (const float*)d_in[5];
  const float* bv = (const float*)d_in[6];
  const float* Wo = (const float*)d_in[7];
  const float* bo = (const float*)d_in[8];

  char* ws = (char*)d_ws;
  u16*   Xb   = (u16*)  (ws + 0);          // 16777216 B (dead after gemm_qkv)
  u16*   Vtg  = (u16*)  (ws + 0);          // aliases Xb, written after
  u16*   Wt   = (u16*)  (ws + 16777216);   //  6291456
  float* bqkv = (float*)(ws + 23068672);   //    12288
  u16*   Wot  = (u16*)  (ws + 23080960);   //  2097152
  u16*   QKV  = (u16*)  (ws + 25178112);   // 50331648
  u16*   MH   = (u16*)  (ws + 75509760);   // 16777216  (total ~92.3 MB)
  float* out  = (float*)d_out;

  k_pack_all    <<<9228, 256, 0, stream>>>(x, Wq, Wk, Wv, bq, bk, bv, Wo,
                                           Xb, Wt, bqkv, Wot);
  k_gemm<0, 2>  <<<dim3(24, 64), 256, 0, stream>>>(Xb, Wt, bqkv, (void*)QKV, 3072);
  k_vt          <<<dim3(32, 64), 256, 0, stream>>>(QKV, Vtg);
  k_attn        <<<dim3(64, 8), 512, 0, stream>>>(QKV, Vtg, MH);
  k_gemm<1, 3>  <<<dim3(8, 64), 256, 0, stream>>>(MH, Wot, bo, (void*)out, 1024);
}